// Round 20
// baseline (71.818 us; speedup 1.0000x reference)
//
#include <hip/hip_runtime.h>
#include <hip/hip_fp16.h>

#define SS 2048
#define L2E 1.44269504088896340736f

typedef _Float16 f16x4 __attribute__((ext_vector_type(4)));
typedef _Float16 f16x8 __attribute__((ext_vector_type(8)));
typedef float f32x4 __attribute__((ext_vector_type(4)));

#define GLDS16(g, l) __builtin_amdgcn_global_load_lds(                          \
    (const __attribute__((address_space(1))) void*)(g),                         \
    (__attribute__((address_space(3))) void*)(l), 16, 0, 0)
#define GLDS4(g, l) __builtin_amdgcn_global_load_lds(                           \
    (const __attribute__((address_space(1))) void*)(g),                         \
    (__attribute__((address_space(3))) void*)(l), 4, 0, 0)

// ---------------- Kernel A: QKV projection via MFMA ----------------
// (byte-identical to round 12 — best measured A)
__global__ __launch_bounds__(256) void qkv_kernel(
    const float* __restrict__ x, const float* __restrict__ Wq,
    const float* __restrict__ Wk, const float* __restrict__ Wv,
    _Float16* __restrict__ qfp, _Float16* __restrict__ kfp,
    _Float16* __restrict__ vfp)
{
    __shared__ float wcs[64 * 96];                    // 24 KB raw weights [f][c96]
    __shared__ __align__(16) _Float16 wfb[12 * 512];  // 12 KB B-fragments

    int t = threadIdx.x;
    int wv = t >> 6, l = t & 63, llo = l & 15, lhi = l >> 4;

    for (int i = t; i < 384; i += 256) {
        float4 v = ((const float4*)Wq)[i];
        int f = (i * 4) / 24, c = (i * 4) % 24;
        *(float4*)&wcs[f * 96 + c] = v;
    }
    for (int i = t; i < 384; i += 256) {
        float4 v = ((const float4*)Wk)[i];
        int f = (i * 4) / 24, c = (i * 4) % 24;
        *(float4*)&wcs[f * 96 + 32 + c] = v;
    }
    for (int i = t; i < 512; i += 256) {
        float4 v = ((const float4*)Wv)[i];
        int f = i >> 3, c = (i * 4) & 31;
        *(float4*)&wcs[f * 96 + 64 + c] = v;
    }
    {   // zero pad cols 24..31 and 56..63
        int f = t >> 2, which = t & 3;
        int c = (which < 2) ? (24 + which * 4) : (56 + (which - 2) * 4);
        *(float4*)&wcs[f * 96 + c] = (float4){0.f, 0.f, 0.f, 0.f};
    }
    __syncthreads();

    #pragma unroll
    for (int p = 0; p < 3; ++p) {
        int sidx = t + p * 256;
        int fr = sidx >> 6, lane = sidx & 63;
        int ct = fr >> 1, kk = fr & 1;
        int lls = lane & 15, lhs = lane >> 4;
        f16x8 wfr;
        #pragma unroll
        for (int j = 0; j < 8; ++j)
            wfr[j] = (_Float16)wcs[(kk * 32 + lhs * 8 + j) * 96 + ct * 16 + lls];
        *(f16x8*)&wfb[fr * 512 + lane * 8] = wfr;
    }
    __syncthreads();

    _Float16* os = (_Float16*)wcs;   // q | k | v fragment staging (aliases wcs)

    if (t < 128) {
        int reg = t >> 6, rr = t & 63;
        *(f16x8*)&os[reg * 2048 + (rr >> 4) * 512 + (48 + (rr & 15)) * 8]
            = (f16x8){0, 0, 0, 0, 0, 0, 0, 0};
    }

    long rowbase = (long)blockIdx.x * 64;
    const float* xr = x + (rowbase + wv * 16 + llo) * 64 + lhi * 8;
    f16x8 a0, a1;
    {
        float4 u0 = *(const float4*)(xr);
        float4 u1 = *(const float4*)(xr + 4);
        float4 u2 = *(const float4*)(xr + 32);
        float4 u3 = *(const float4*)(xr + 36);
        a0[0] = (_Float16)u0.x; a0[1] = (_Float16)u0.y;
        a0[2] = (_Float16)u0.z; a0[3] = (_Float16)u0.w;
        a0[4] = (_Float16)u1.x; a0[5] = (_Float16)u1.y;
        a0[6] = (_Float16)u1.z; a0[7] = (_Float16)u1.w;
        a1[0] = (_Float16)u2.x; a1[1] = (_Float16)u2.y;
        a1[2] = (_Float16)u2.z; a1[3] = (_Float16)u2.w;
        a1[4] = (_Float16)u3.x; a1[5] = (_Float16)u3.y;
        a1[6] = (_Float16)u3.z; a1[7] = (_Float16)u3.w;
    }

    f32x4 d[6];
    #pragma unroll
    for (int ct = 0; ct < 6; ++ct) {
        f16x8 b0 = *(const f16x8*)&wfb[(ct * 2 + 0) * 512 + l * 8];
        f16x8 b1 = *(const f16x8*)&wfb[(ct * 2 + 1) * 512 + l * 8];
        d[ct] = __builtin_amdgcn_mfma_f32_16x16x32_f16(a0, b0,
                  (f32x4){0.f, 0.f, 0.f, 0.f}, 0, 0, 0);
        d[ct] = __builtin_amdgcn_mfma_f32_16x16x32_f16(a1, b1, d[ct], 0, 0, 0);
    }

    #pragma unroll
    for (int r = 0; r < 4; ++r) {
        int sl = lhi * 4 + r;
        os[wv * 512 + ((llo >> 3) * 16 + sl) * 8 + (llo & 7)]
            = (_Float16)(d[0][r] * L2E);
        if (llo < 8)
            os[wv * 512 + (32 + sl) * 8 + llo] = (_Float16)(d[1][r] * L2E);
        os[2048 + wv * 512 + ((llo >> 3) * 16 + sl) * 8 + (llo & 7)]
            = (_Float16)d[2][r];
        if (llo < 8)
            os[2048 + wv * 512 + (32 + sl) * 8 + llo] = (_Float16)d[3][r];
        os[4096 + wv * 512 + (lhi * 16 + llo) * 8 + r]     = (_Float16)d[4][r];
        os[4096 + wv * 512 + (lhi * 16 + llo) * 8 + 4 + r] = (_Float16)d[5][r];
    }
    __syncthreads();

    long blk = blockIdx.x;
    *(f16x8*)(qfp + blk * 2048 + t * 8) = *(const f16x8*)&os[t * 8];
    *(f16x8*)(kfp + blk * 2048 + t * 8) = *(const f16x8*)&os[2048 + t * 8];
    *(f16x8*)(vfp + blk * 2048 + t * 8) = *(const f16x8*)&os[4096 + t * 8];
}

// ---------------- Kernel B: column-softmax partials, 32 waves/CU ----------
// r19's proven triple-buffer/counted-vmcnt skeleton, but grid 2048 =
// (32 b x 32 kb x 2 qh): each block streams HALF the q (1024 = 16 tiles).
// 8 blocks/CU x 4 waves = 32 waves/CU (2x TLP vs every prior B variant).
// Writes zpart[qh][b][k]; finalize sums the 2 partials.
__global__ __launch_bounds__(256) void stats_kernel(
    const _Float16* __restrict__ qf, const _Float16* __restrict__ kf,
    float* __restrict__ zpart)
{
    __shared__ __align__(16) _Float16 qtile[3][2048];  // 3 x 4 KB
    int w = blockIdx.x;
    int b = w >> 6, rest = w & 63;
    int kb = rest >> 1, qh = rest & 1;
    int t = threadIdx.x;
    int wv = t >> 6, l = t & 63, llo = l & 15, lhi = l >> 4;

    // stationary K-frag: k rows (kb*4+wv)*16 .. +15
    f16x8 af = *(const f16x8*)(kf + ((long)b * 128 + kb * 4 + wv) * 512 + l * 8);
    const _Float16* qsrc = qf + (long)b * 65536 + (long)qh * 32768 + wv * 512 + l * 8;

    f32x4 z = {0.f, 0.f, 0.f, 0.f};

    // prologue: 2 stages in flight
    GLDS16(qsrc,        &qtile[0][wv * 512]);
    GLDS16(qsrc + 2048, &qtile[1][wv * 512]);

    for (int tile = 0; tile < 15; ++tile) {
        asm volatile("s_waitcnt vmcnt(1)" ::: "memory");  // stage(tile) landed
        __builtin_amdgcn_s_barrier();
        __builtin_amdgcn_sched_barrier(0);
        if (tile < 14)
            GLDS16(qsrc + (long)(tile + 2) * 2048, &qtile[(tile + 2) % 3][wv * 512]);
        const _Float16* Qb = &qtile[tile % 3][0];
        #pragma unroll
        for (int fi = 0; fi < 4; ++fi) {
            f16x8 q0 = *(const f16x8*)(Qb + fi * 512 + l * 8);
            f32x4 d = __builtin_amdgcn_mfma_f32_16x16x32_f16(af, q0,
                        (f32x4){0.f, 0.f, 0.f, 0.f}, 0, 0, 0);
            #pragma unroll
            for (int r = 0; r < 4; ++r) z[r] += __builtin_amdgcn_exp2f(d[r]);
        }
    }
    // peeled last tile (15): full drain
    asm volatile("s_waitcnt vmcnt(0)" ::: "memory");
    __builtin_amdgcn_s_barrier();
    __builtin_amdgcn_sched_barrier(0);
    {
        const _Float16* Qb = &qtile[15 % 3][0];
        #pragma unroll
        for (int fi = 0; fi < 4; ++fi) {
            f16x8 q0 = *(const f16x8*)(Qb + fi * 512 + l * 8);
            f32x4 d = __builtin_amdgcn_mfma_f32_16x16x32_f16(af, q0,
                        (f32x4){0.f, 0.f, 0.f, 0.f}, 0, 0, 0);
            #pragma unroll
            for (int r = 0; r < 4; ++r) z[r] += __builtin_amdgcn_exp2f(d[r]);
        }
    }
    // sum over the 16 q-columns (lane bits 0..3)
    #pragma unroll
    for (int m = 1; m < 16; m <<= 1)
        #pragma unroll
        for (int r = 0; r < 4; ++r) z[r] += __shfl_xor(z[r], m, 64);
    if (llo == 0) {
        #pragma unroll
        for (int r = 0; r < 4; ++r)
            zpart[((long)qh * 32 + b) * SS + (kb * 4 + wv) * 16 + lhi * 4 + r] = z[r];
    }
}

// ---------------- Kernel B2: finalize wneg = -log2(sum of 2 partials) ------
__global__ __launch_bounds__(256) void finalize_kernel(
    const float* __restrict__ zpart, float* __restrict__ wneg)
{
    int i = blockIdx.x * 256 + threadIdx.x;   // 65536 total
    float s = zpart[i] + zpart[32 * SS + i];
    wneg[i] = -__builtin_amdgcn_logf(s);
}

// ---------------- Kernel C: attention + output projection ----------------
// (byte-identical to round 16 — K_TILE=128, PASSING)
__global__ __launch_bounds__(256) void attn_out_kernel(
    const _Float16* __restrict__ qf, const _Float16* __restrict__ kf,
    const _Float16* __restrict__ vf, const float* __restrict__ wneg,
    const float* __restrict__ Wh, float* __restrict__ out)
{
    __shared__ __align__(16) _Float16 lds[2][8448];  // K 4096 | V 4096 | w 128 f32

    int w = blockIdx.x;
    int b = w >> 5, qblk = w & 31;
    int t = threadIdx.x;
    int wv = t >> 6, l = t & 63, llo = l & 15, lhi = l >> 4;
    int q0 = qblk * 64 + wv * 16;

    f16x8 qfr = *(const f16x8*)(qf + ((long)b * 128 + qblk * 4 + wv) * 512 + l * 8);

    f16x4 whlo[4], whhi[4];
    #pragma unroll
    for (int fb = 0; fb < 4; ++fb)
        #pragma unroll
        for (int j = 0; j < 4; ++j) {
            whlo[fb][j] = (_Float16)Wh[(4 * lhi + j) * 64 + fb * 16 + llo];
            whhi[fb][j] = (_Float16)Wh[(16 + 4 * lhi + j) * 64 + fb * 16 + llo];
        }

    const _Float16* kgb = kf + ((long)b * 128 + wv) * 512 + l * 8;   // + phase*4096
    const _Float16* vgb = vf + (long)b * 65536 + wv * 512 + l * 8;   // + phase*4096
    const float*    wgb = wneg + (long)b * SS + l;                   // + phase*128

    f32x4 acc0 = {0,0,0,0}, acc1 = {0,0,0,0};

    GLDS16(kgb,        &lds[0][wv * 512]);
    GLDS16(kgb + 2048, &lds[0][2048 + wv * 512]);
    GLDS16(vgb,        &lds[0][4096 + wv * 512]);
    GLDS16(vgb + 2048, &lds[0][6144 + wv * 512]);
    if (wv == 0) {
        GLDS4(wgb,      (float*)&lds[0][8192]);
        GLDS4(wgb + 64, (float*)&lds[0][8320]);
    }

    for (int ph = 0; ph < 16; ++ph) {
        int cb = ph & 1;
        __syncthreads();
        if (ph < 15) {
            long base = (long)(ph + 1) * 4096;
            GLDS16(kgb + base,        &lds[cb ^ 1][wv * 512]);
            GLDS16(kgb + base + 2048, &lds[cb ^ 1][2048 + wv * 512]);
            GLDS16(vgb + base,        &lds[cb ^ 1][4096 + wv * 512]);
            GLDS16(vgb + base + 2048, &lds[cb ^ 1][6144 + wv * 512]);
            if (wv == 0) {
                GLDS4(wgb + (ph + 1) * 128,      (float*)&lds[cb ^ 1][8192]);
                GLDS4(wgb + (ph + 1) * 128 + 64, (float*)&lds[cb ^ 1][8320]);
            }
        }
        const _Float16* Kb = &lds[cb][0];
        const _Float16* Vb = &lds[cb][4096];
        const float*    Wb = (const float*)&lds[cb][8192];
        #pragma unroll
        for (int t4 = 0; t4 < 8; ++t4) {
            f16x8 kfr = *(const f16x8*)(Kb + t4 * 512 + l * 8);
            float4 w4 = *(const float4*)(Wb + t4 * 16 + lhi * 4);
            f32x4 d = __builtin_amdgcn_mfma_f32_16x16x32_f16(kfr, qfr,
                        (f32x4){w4.x, w4.y, w4.z, w4.w}, 0, 0, 0);
            f16x4 pa;
            #pragma unroll
            for (int r = 0; r < 4; ++r) pa[r] = (_Float16)__builtin_amdgcn_exp2f(d[r]);
            f16x8 v01 = *(const f16x8*)(Vb + t4 * 512 + l * 8);
            f16x4 v0 = {v01[0], v01[1], v01[2], v01[3]};
            f16x4 v1 = {v01[4], v01[5], v01[6], v01[7]};
            acc0 = __builtin_amdgcn_mfma_f32_16x16x16f16(v0, pa, acc0, 0, 0, 0);
            acc1 = __builtin_amdgcn_mfma_f32_16x16x16f16(v1, pa, acc1, 0, 0, 0);
        }
    }

    f16x4 h0, h1;
    #pragma unroll
    for (int r = 0; r < 4; ++r) {
        h0[r] = (_Float16)acc0[r];
        h1[r] = (_Float16)acc1[r];
    }
    float* orow = out + ((long)b * SS + q0 + llo) * 64 + 4 * lhi;
    #pragma unroll
    for (int fb = 0; fb < 4; ++fb) {
        f32x4 o = __builtin_amdgcn_mfma_f32_16x16x16f16(whlo[fb], h0,
                    (f32x4){0.f, 0.f, 0.f, 0.f}, 0, 0, 0);
        o = __builtin_amdgcn_mfma_f32_16x16x16f16(whhi[fb], h1, o, 0, 0, 0);
        *(f32x4*)(orow + fb * 16) = o;
    }
}

extern "C" void kernel_launch(void* const* d_in, const int* in_sizes, int n_in,
                              void* d_out, int out_size, void* d_ws, size_t ws_size,
                              hipStream_t stream) {
    const float* x  = (const float*)d_in[0];
    const float* Wq = (const float*)d_in[1];
    const float* Wk = (const float*)d_in[2];
    const float* Wv = (const float*)d_in[3];
    const float* Wh = (const float*)d_in[4];
    float* out = (float*)d_out;

    char* ws = (char*)d_ws;
    _Float16* qf  = (_Float16*)(ws);                           // 4 MB
    _Float16* kf  = (_Float16*)(ws + (4l << 20));              // 4 MB
    _Float16* vf  = (_Float16*)(ws + (8l << 20));              // 4 MB
    float* wneg   = (float*)(ws + (12l << 20));                // 256 KB
    float* zpart  = (float*)(ws + (12l << 20) + (256l << 10)); // 512 KB (2 slices)

    qkv_kernel<<<1024, 256, 0, stream>>>(x, Wq, Wk, Wv, qf, kf, vf);
    stats_kernel<<<2048, 256, 0, stream>>>(qf, kf, zpart);
    finalize_kernel<<<256, 256, 0, stream>>>(zpart, wneg);
    attn_out_kernel<<<1024, 256, 0, stream>>>(qf, kf, vf, wneg, Wh, out);
}

// Round 23
// 69.442 us; speedup vs baseline: 1.0342x; 1.0342x over previous
//
#include <hip/hip_runtime.h>
#include <hip/hip_fp16.h>

#define SS 2048
#define L2E 1.44269504088896340736f

typedef _Float16 f16x4 __attribute__((ext_vector_type(4)));
typedef _Float16 f16x8 __attribute__((ext_vector_type(8)));
typedef float f32x4 __attribute__((ext_vector_type(4)));

#define GLDS16(g, l) __builtin_amdgcn_global_load_lds(                          \
    (const __attribute__((address_space(1))) void*)(g),                         \
    (__attribute__((address_space(3))) void*)(l), 16, 0, 0)
#define GLDS4(g, l) __builtin_amdgcn_global_load_lds(                           \
    (const __attribute__((address_space(1))) void*)(g),                         \
    (__attribute__((address_space(3))) void*)(l), 4, 0, 0)

// ---------------- Kernel A: QKV projection via MFMA ----------------
// (byte-identical to round 12 — best measured A)
__global__ __launch_bounds__(256) void qkv_kernel(
    const float* __restrict__ x, const float* __restrict__ Wq,
    const float* __restrict__ Wk, const float* __restrict__ Wv,
    _Float16* __restrict__ qfp, _Float16* __restrict__ kfp,
    _Float16* __restrict__ vfp)
{
    __shared__ float wcs[64 * 96];                    // 24 KB raw weights [f][c96]
    __shared__ __align__(16) _Float16 wfb[12 * 512];  // 12 KB B-fragments

    int t = threadIdx.x;
    int wv = t >> 6, l = t & 63, llo = l & 15, lhi = l >> 4;

    for (int i = t; i < 384; i += 256) {
        float4 v = ((const float4*)Wq)[i];
        int f = (i * 4) / 24, c = (i * 4) % 24;
        *(float4*)&wcs[f * 96 + c] = v;
    }
    for (int i = t; i < 384; i += 256) {
        float4 v = ((const float4*)Wk)[i];
        int f = (i * 4) / 24, c = (i * 4) % 24;
        *(float4*)&wcs[f * 96 + 32 + c] = v;
    }
    for (int i = t; i < 512; i += 256) {
        float4 v = ((const float4*)Wv)[i];
        int f = i >> 3, c = (i * 4) & 31;
        *(float4*)&wcs[f * 96 + 64 + c] = v;
    }
    {   // zero pad cols 24..31 and 56..63
        int f = t >> 2, which = t & 3;
        int c = (which < 2) ? (24 + which * 4) : (56 + (which - 2) * 4);
        *(float4*)&wcs[f * 96 + c] = (float4){0.f, 0.f, 0.f, 0.f};
    }
    __syncthreads();

    #pragma unroll
    for (int p = 0; p < 3; ++p) {
        int sidx = t + p * 256;
        int fr = sidx >> 6, lane = sidx & 63;
        int ct = fr >> 1, kk = fr & 1;
        int lls = lane & 15, lhs = lane >> 4;
        f16x8 wfr;
        #pragma unroll
        for (int j = 0; j < 8; ++j)
            wfr[j] = (_Float16)wcs[(kk * 32 + lhs * 8 + j) * 96 + ct * 16 + lls];
        *(f16x8*)&wfb[fr * 512 + lane * 8] = wfr;
    }
    __syncthreads();

    _Float16* os = (_Float16*)wcs;   // q | k | v fragment staging (aliases wcs)

    if (t < 128) {
        int reg = t >> 6, rr = t & 63;
        *(f16x8*)&os[reg * 2048 + (rr >> 4) * 512 + (48 + (rr & 15)) * 8]
            = (f16x8){0, 0, 0, 0, 0, 0, 0, 0};
    }

    long rowbase = (long)blockIdx.x * 64;
    const float* xr = x + (rowbase + wv * 16 + llo) * 64 + lhi * 8;
    f16x8 a0, a1;
    {
        float4 u0 = *(const float4*)(xr);
        float4 u1 = *(const float4*)(xr + 4);
        float4 u2 = *(const float4*)(xr + 32);
        float4 u3 = *(const float4*)(xr + 36);
        a0[0] = (_Float16)u0.x; a0[1] = (_Float16)u0.y;
        a0[2] = (_Float16)u0.z; a0[3] = (_Float16)u0.w;
        a0[4] = (_Float16)u1.x; a0[5] = (_Float16)u1.y;
        a0[6] = (_Float16)u1.z; a0[7] = (_Float16)u1.w;
        a1[0] = (_Float16)u2.x; a1[1] = (_Float16)u2.y;
        a1[2] = (_Float16)u2.z; a1[3] = (_Float16)u2.w;
        a1[4] = (_Float16)u3.x; a1[5] = (_Float16)u3.y;
        a1[6] = (_Float16)u3.z; a1[7] = (_Float16)u3.w;
    }

    f32x4 d[6];
    #pragma unroll
    for (int ct = 0; ct < 6; ++ct) {
        f16x8 b0 = *(const f16x8*)&wfb[(ct * 2 + 0) * 512 + l * 8];
        f16x8 b1 = *(const f16x8*)&wfb[(ct * 2 + 1) * 512 + l * 8];
        d[ct] = __builtin_amdgcn_mfma_f32_16x16x32_f16(a0, b0,
                  (f32x4){0.f, 0.f, 0.f, 0.f}, 0, 0, 0);
        d[ct] = __builtin_amdgcn_mfma_f32_16x16x32_f16(a1, b1, d[ct], 0, 0, 0);
    }

    #pragma unroll
    for (int r = 0; r < 4; ++r) {
        int sl = lhi * 4 + r;
        os[wv * 512 + ((llo >> 3) * 16 + sl) * 8 + (llo & 7)]
            = (_Float16)(d[0][r] * L2E);
        if (llo < 8)
            os[wv * 512 + (32 + sl) * 8 + llo] = (_Float16)(d[1][r] * L2E);
        os[2048 + wv * 512 + ((llo >> 3) * 16 + sl) * 8 + (llo & 7)]
            = (_Float16)d[2][r];
        if (llo < 8)
            os[2048 + wv * 512 + (32 + sl) * 8 + llo] = (_Float16)d[3][r];
        os[4096 + wv * 512 + (lhi * 16 + llo) * 8 + r]     = (_Float16)d[4][r];
        os[4096 + wv * 512 + (lhi * 16 + llo) * 8 + 4 + r] = (_Float16)d[5][r];
    }
    __syncthreads();

    long blk = blockIdx.x;
    *(f16x8*)(qfp + blk * 2048 + t * 8) = *(const f16x8*)&os[t * 8];
    *(f16x8*)(kfp + blk * 2048 + t * 8) = *(const f16x8*)&os[2048 + t * 8];
    *(f16x8*)(vfp + blk * 2048 + t * 8) = *(const f16x8*)&os[4096 + t * 8];
}

// ---------------- Kernel B: fused column-softmax stats, 16 phases ----------
// r18's PASSING fused structure with 8 KB q-tiles (16 phases instead of 32):
// each wave stages 2 fragments per phase. The r18 correctness pattern
// (vmcnt(0) before barrier + sched_barrier(0) after) is unchanged.
__global__ __launch_bounds__(256) void stats_kernel(
    const _Float16* __restrict__ qf, const _Float16* __restrict__ kf,
    float* __restrict__ wneg)
{
    __shared__ __align__(16) _Float16 qtile[2][4096];  // 2 x 8 KB
    int w = blockIdx.x;
    int b = w >> 5, kb = w & 31;
    int t = threadIdx.x;
    int wv = t >> 6, l = t & 63, llo = l & 15, lhi = l >> 4;

    // stationary K-frag: k rows (kb*4+wv)*16 .. +15
    f16x8 af = *(const f16x8*)(kf + ((long)b * 128 + kb * 4 + wv) * 512 + l * 8);
    const _Float16* qsrc = qf + (long)b * 65536 + wv * 512 + l * 8;

    f32x4 z = {0.f, 0.f, 0.f, 0.f};

    // stage phase 0 (frags wv and wv+4)
    GLDS16(qsrc,        &qtile[0][wv * 512]);
    GLDS16(qsrc + 2048, &qtile[0][2048 + wv * 512]);

    for (int ph = 0; ph < 16; ++ph) {
        int cb = ph & 1;
        asm volatile("s_waitcnt vmcnt(0)" ::: "memory");  // own stages landed
        __syncthreads();                                   // all waves' stages landed
        __builtin_amdgcn_sched_barrier(0);                 // no hoist across barrier
        if (ph < 15) {
            long base = (long)(ph + 1) * 4096;
            GLDS16(qsrc + base,        &qtile[cb ^ 1][wv * 512]);
            GLDS16(qsrc + base + 2048, &qtile[cb ^ 1][2048 + wv * 512]);
        }
        const _Float16* Qb = &qtile[cb][0];
        #pragma unroll
        for (int fi = 0; fi < 8; ++fi) {
            f16x8 q0 = *(const f16x8*)(Qb + fi * 512 + l * 8);
            f32x4 d = __builtin_amdgcn_mfma_f32_16x16x32_f16(af, q0,
                        (f32x4){0.f, 0.f, 0.f, 0.f}, 0, 0, 0);
            #pragma unroll
            for (int r = 0; r < 4; ++r) z[r] += __builtin_amdgcn_exp2f(d[r]);
        }
    }
    // sum over the 16 q-columns (lane bits 0..3)
    #pragma unroll
    for (int m = 1; m < 16; m <<= 1)
        #pragma unroll
        for (int r = 0; r < 4; ++r) z[r] += __shfl_xor(z[r], m, 64);
    if (llo == 0) {
        #pragma unroll
        for (int r = 0; r < 4; ++r)
            wneg[(long)b * SS + (kb * 4 + wv) * 16 + lhi * 4 + r]
                = -__builtin_amdgcn_logf(z[r]);
    }
}

// ---------------- Kernel C: attention + output projection ----------------
// (byte-identical to round 16 — K_TILE=128, PASSING)
__global__ __launch_bounds__(256) void attn_out_kernel(
    const _Float16* __restrict__ qf, const _Float16* __restrict__ kf,
    const _Float16* __restrict__ vf, const float* __restrict__ wneg,
    const float* __restrict__ Wh, float* __restrict__ out)
{
    __shared__ __align__(16) _Float16 lds[2][8448];  // K 4096 | V 4096 | w 128 f32

    int w = blockIdx.x;
    int b = w >> 5, qblk = w & 31;
    int t = threadIdx.x;
    int wv = t >> 6, l = t & 63, llo = l & 15, lhi = l >> 4;
    int q0 = qblk * 64 + wv * 16;

    f16x8 qfr = *(const f16x8*)(qf + ((long)b * 128 + qblk * 4 + wv) * 512 + l * 8);

    f16x4 whlo[4], whhi[4];
    #pragma unroll
    for (int fb = 0; fb < 4; ++fb)
        #pragma unroll
        for (int j = 0; j < 4; ++j) {
            whlo[fb][j] = (_Float16)Wh[(4 * lhi + j) * 64 + fb * 16 + llo];
            whhi[fb][j] = (_Float16)Wh[(16 + 4 * lhi + j) * 64 + fb * 16 + llo];
        }

    const _Float16* kgb = kf + ((long)b * 128 + wv) * 512 + l * 8;   // + phase*4096
    const _Float16* vgb = vf + (long)b * 65536 + wv * 512 + l * 8;   // + phase*4096
    const float*    wgb = wneg + (long)b * SS + l;                   // + phase*128

    f32x4 acc0 = {0,0,0,0}, acc1 = {0,0,0,0};

    GLDS16(kgb,        &lds[0][wv * 512]);
    GLDS16(kgb + 2048, &lds[0][2048 + wv * 512]);
    GLDS16(vgb,        &lds[0][4096 + wv * 512]);
    GLDS16(vgb + 2048, &lds[0][6144 + wv * 512]);
    if (wv == 0) {
        GLDS4(wgb,      (float*)&lds[0][8192]);
        GLDS4(wgb + 64, (float*)&lds[0][8320]);
    }

    for (int ph = 0; ph < 16; ++ph) {
        int cb = ph & 1;
        __syncthreads();
        if (ph < 15) {
            long base = (long)(ph + 1) * 4096;
            GLDS16(kgb + base,        &lds[cb ^ 1][wv * 512]);
            GLDS16(kgb + base + 2048, &lds[cb ^ 1][2048 + wv * 512]);
            GLDS16(vgb + base,        &lds[cb ^ 1][4096 + wv * 512]);
            GLDS16(vgb + base + 2048, &lds[cb ^ 1][6144 + wv * 512]);
            if (wv == 0) {
                GLDS4(wgb + (ph + 1) * 128,      (float*)&lds[cb ^ 1][8192]);
                GLDS4(wgb + (ph + 1) * 128 + 64, (float*)&lds[cb ^ 1][8320]);
            }
        }
        const _Float16* Kb = &lds[cb][0];
        const _Float16* Vb = &lds[cb][4096];
        const float*    Wb = (const float*)&lds[cb][8192];
        #pragma unroll
        for (int t4 = 0; t4 < 8; ++t4) {
            f16x8 kfr = *(const f16x8*)(Kb + t4 * 512 + l * 8);
            float4 w4 = *(const float4*)(Wb + t4 * 16 + lhi * 4);
            f32x4 d = __builtin_amdgcn_mfma_f32_16x16x32_f16(kfr, qfr,
                        (f32x4){w4.x, w4.y, w4.z, w4.w}, 0, 0, 0);
            f16x4 pa;
            #pragma unroll
            for (int r = 0; r < 4; ++r) pa[r] = (_Float16)__builtin_amdgcn_exp2f(d[r]);
            f16x8 v01 = *(const f16x8*)(Vb + t4 * 512 + l * 8);
            f16x4 v0 = {v01[0], v01[1], v01[2], v01[3]};
            f16x4 v1 = {v01[4], v01[5], v01[6], v01[7]};
            acc0 = __builtin_amdgcn_mfma_f32_16x16x16f16(v0, pa, acc0, 0, 0, 0);
            acc1 = __builtin_amdgcn_mfma_f32_16x16x16f16(v1, pa, acc1, 0, 0, 0);
        }
    }

    f16x4 h0, h1;
    #pragma unroll
    for (int r = 0; r < 4; ++r) {
        h0[r] = (_Float16)acc0[r];
        h1[r] = (_Float16)acc1[r];
    }
    float* orow = out + ((long)b * SS + q0 + llo) * 64 + 4 * lhi;
    #pragma unroll
    for (int fb = 0; fb < 4; ++fb) {
        f32x4 o = __builtin_amdgcn_mfma_f32_16x16x16f16(whlo[fb], h0,
                    (f32x4){0.f, 0.f, 0.f, 0.f}, 0, 0, 0);
        o = __builtin_amdgcn_mfma_f32_16x16x16f16(whhi[fb], h1, o, 0, 0, 0);
        *(f32x4*)(orow + fb * 16) = o;
    }
}

extern "C" void kernel_launch(void* const* d_in, const int* in_sizes, int n_in,
                              void* d_out, int out_size, void* d_ws, size_t ws_size,
                              hipStream_t stream) {
    const float* x  = (const float*)d_in[0];
    const float* Wq = (const float*)d_in[1];
    const float* Wk = (const float*)d_in[2];
    const float* Wv = (const float*)d_in[3];
    const float* Wh = (const float*)d_in[4];
    float* out = (float*)d_out;

    char* ws = (char*)d_ws;
    _Float16* qf  = (_Float16*)(ws);                           // 4 MB
    _Float16* kf  = (_Float16*)(ws + (4l << 20));              // 4 MB
    _Float16* vf  = (_Float16*)(ws + (8l << 20));              // 4 MB
    float* wneg   = (float*)(ws + (12l << 20));                // 256 KB

    qkv_kernel<<<1024, 256, 0, stream>>>(x, Wq, Wk, Wv, qf, kf, vf);
    stats_kernel<<<1024, 256, 0, stream>>>(qf, kf, wneg);
    attn_out_kernel<<<1024, 256, 0, stream>>>(qf, kf, vf, wneg, Wh, out);
}